// Round 17
// baseline (179.532 us; speedup 1.0000x reference)
//
#include <hip/hip_runtime.h>

#define IN_NUM 1152
#define OUT_NUM 10
#define OUT_DIM 16
#define IN_DIM 8
#define NB 256
#define KTOT 9216

// workspace float offsets
#define OFF_SPART 0
#define SZ_SPART (96 * OUT_NUM * OUT_DIM * NB)        // 3,932,160
#define OFF_BP (OFF_SPART + SZ_SPART)
#define SZ_BP (64 * IN_NUM * OUT_NUM)                 // 737,280 (8 bq x 8 c rows)
#define OFF_VT (OFF_BP + SZ_BP)
#define SZ_VT (NB * OUT_NUM * OUT_DIM)                // 40,960
#define OFF_WT (OFF_VT + SZ_VT)
#define SZ_WT (OUT_NUM * OUT_DIM * KTOT)              // Wt[j][d][k]
#define OFF_WT2 (OFF_WT + SZ_WT)
#define SZ_WT2 (OUT_NUM * KTOT * OUT_DIM)             // Wt2[j][k][d]

typedef short bf16x8 __attribute__((ext_vector_type(8)));
typedef float f32x4 __attribute__((ext_vector_type(4)));

__device__ __forceinline__ unsigned short f2bf(float f) {
    unsigned u = __float_as_uint(f);
    u = (u + 0x7FFFu + ((u >> 16) & 1u)) >> 16;   // round-to-nearest-even
    return (unsigned short)u;
}

// ---- prep: Wt[j][d*8+c][i], Wt2[j][c*1152+i][d] = W[i][j][d][c] ----
__global__ __launch_bounds__(256) void k_prep(const float* __restrict__ W,
                                              float* __restrict__ Wt,
                                              float* __restrict__ Wt2) {
    __shared__ float lds2[32][129];
    int u = blockIdx.x, t = threadIdx.x;
    int itile = u / 10, j = u - itile * 10;
    int i0 = itile * 32;
    int r0 = t >> 5, c4b = t & 31;
#pragma unroll
    for (int rr = 0; rr < 4; ++rr) {
        int rrow = rr * 8 + r0;
        float4 w4 = *reinterpret_cast<const float4*>(
            &W[(size_t)(i0 + rrow) * 1280 + j * 128 + c4b * 4]);
        lds2[rrow][c4b * 4 + 0] = w4.x; lds2[rrow][c4b * 4 + 1] = w4.y;
        lds2[rrow][c4b * 4 + 2] = w4.z; lds2[rrow][c4b * 4 + 3] = w4.w;
    }
    __syncthreads();
    int ii = t & 31, dcq = t >> 5;
#pragma unroll
    for (int rr = 0; rr < 16; ++rr) {
        int dc = rr * 8 + dcq;
        Wt[(size_t)(j * 128 + dc) * IN_NUM + i0 + ii] = lds2[ii][dc];
    }
    int d4 = t & 3, ii2 = (t >> 2) & 31, ch0 = t >> 7;
#pragma unroll
    for (int c2 = 0; c2 < 4; ++c2) {
        int c = c2 * 2 + ch0;
        float4 o;
        o.x = lds2[ii2][(d4 * 4 + 0) * 8 + c];
        o.y = lds2[ii2][(d4 * 4 + 1) * 8 + c];
        o.z = lds2[ii2][(d4 * 4 + 2) * 8 + c];
        o.w = lds2[ii2][(d4 * 4 + 3) * 8 + c];
        *reinterpret_cast<float4*>(
            &Wt2[((size_t)j * KTOT + c * IN_NUM + i0 + ii2) * OUT_DIM + d4 * 4]) = o;
    }
}

// ---- p1 (MFMA, R16-validated): spart[isp][j][d][b] = sum_k (ldc[k]*W[k,d]) * x[b,k] ----
__global__ __launch_bounds__(256, 4) void k_p1(const float* __restrict__ x,
                                               const float* __restrict__ Wt2,
                                               const float* __restrict__ bp,
                                               float* __restrict__ spart, int it) {
    __shared__ float ldc[96];
    __shared__ unsigned short atT[16][100];
    int w = blockIdx.x, t = threadIdx.x;
    int g8 = w / 80, r = w - g8 * 80;
    int j = r >> 3, isp = g8 * 8 + (r & 7);   // same-isp j-group 8 apart -> same XCD
    int cch = isp / 12;
    int i0 = (isp - cch * 12) * 96;
    int k0 = isp * 96;
    if (t < 96) {
        float cv;
        if (it == 0) {
            cv = 0.1f;
        } else {
            int i = i0 + t;
            float bt_[OUT_NUM];
#pragma unroll
            for (int jp = 0; jp < OUT_NUM; ++jp) bt_[jp] = 0.f;
#pragma unroll 4
            for (int row = 0; row < 64; ++row) {   // 8 bq x 8 c partial rows
                const float2* p2 = reinterpret_cast<const float2*>(
                    &bp[(size_t)row * (IN_NUM * OUT_NUM) + i * OUT_NUM]);
#pragma unroll
                for (int q = 0; q < 5; ++q) {
                    float2 v = p2[q];
                    bt_[q * 2] += v.x; bt_[q * 2 + 1] += v.y;
                }
            }
            float m = -1e30f;
#pragma unroll
            for (int jp = 0; jp < OUT_NUM; ++jp) { bt_[jp] *= (1.f / NB); m = fmaxf(m, bt_[jp]); }
            float s = 0.f;
#pragma unroll
            for (int jp = 0; jp < OUT_NUM; ++jp) { bt_[jp] = __expf(bt_[jp] - m); s += bt_[jp]; }
            cv = bt_[j] / s;
        }
        ldc[t] = cv;
    }
    __syncthreads();
    for (int e = t; e < 1536; e += 256) {
        int d = e & 15, kk = e >> 4;
        atT[d][kk] = f2bf(ldc[kk] * Wt2[((size_t)j * KTOT + k0 + kk) * OUT_DIM + d]);
    }
    __syncthreads();
    int lane = t & 63, wv = t >> 6;
    int lg = lane >> 4, lm = lane & 15;
    bf16x8 bfr[3];
#pragma unroll
    for (int ks = 0; ks < 3; ++ks) {
        const unsigned short* p0 = &atT[lm][ks * 32 + lg * 4];
        ushort4 u0 = *reinterpret_cast<const ushort4*>(p0);
        ushort4 u1 = *reinterpret_cast<const ushort4*>(p0 + 16);
        bfr[ks][0] = (short)u0.x; bfr[ks][1] = (short)u0.y;
        bfr[ks][2] = (short)u0.z; bfr[ks][3] = (short)u0.w;
        bfr[ks][4] = (short)u1.x; bfr[ks][5] = (short)u1.y;
        bfr[ks][6] = (short)u1.z; bfr[ks][7] = (short)u1.w;
    }
    float* sp = spart + ((size_t)isp * OUT_NUM + j) * (OUT_DIM * NB);
#pragma unroll
    for (int tb = 0; tb < 4; ++tb) {
        int tbase = (wv * 4 + tb) * 16;
        const float* xr = x + (size_t)(tbase + lm) * KTOT + k0 + lg * 4;
        f32x4 acc = {0.f, 0.f, 0.f, 0.f};
#pragma unroll
        for (int ks = 0; ks < 3; ++ks) {
            float4 a0 = *reinterpret_cast<const float4*>(xr + ks * 32);
            float4 a1 = *reinterpret_cast<const float4*>(xr + ks * 32 + 16);
            bf16x8 af;
            af[0] = (short)f2bf(a0.x); af[1] = (short)f2bf(a0.y);
            af[2] = (short)f2bf(a0.z); af[3] = (short)f2bf(a0.w);
            af[4] = (short)f2bf(a1.x); af[5] = (short)f2bf(a1.y);
            af[6] = (short)f2bf(a1.z); af[7] = (short)f2bf(a1.w);
            acc = __builtin_amdgcn_mfma_f32_16x16x32_bf16(af, bfr[ks], acc, 0, 0, 0);
        }
        *reinterpret_cast<float4*>(&sp[(size_t)lm * NB + tbase + lg * 4]) =
            make_float4(acc[0], acc[1], acc[2], acc[3]);
    }
}

// ---- p2: reduce spart over isp, squash, write dst[b][j][d] (R11 verbatim) ----
__global__ __launch_bounds__(256, 4) void k_p2(const float* __restrict__ spart,
                                               float* __restrict__ dst) {
    __shared__ float smem[4672];
    float (*red)[32][17] = (float (*)[32][17])smem;
    float (*nrm)[9] = (float (*)[9])(smem + 4352);
    float* cf = smem + 4640;
    int wvar = blockIdx.x, t = threadIdx.x;
    int j = wvar >> 3, bt2 = wvar & 7;
    int ie = t >> 5, bb = t & 31;
    int b = bt2 * 32 + bb;
    float acc[16];
#pragma unroll
    for (int d = 0; d < 16; ++d) acc[d] = 0.f;
    for (int q = 0; q < 12; ++q) {
        int isp = ie * 12 + q;
        const float* sp = spart + (size_t)(isp * OUT_NUM + j) * (OUT_DIM * NB) + b;
#pragma unroll
        for (int d = 0; d < 16; ++d) acc[d] += sp[d * NB];
    }
#pragma unroll
    for (int d = 0; d < 16; ++d) red[ie][bb][d] = acc[d];
    __syncthreads();
    int bb2 = t >> 3, dp = t & 7;
    float s0 = 0.f, s1 = 0.f;
#pragma unroll
    for (int e = 0; e < 8; ++e) { s0 += red[e][bb2][dp * 2]; s1 += red[e][bb2][dp * 2 + 1]; }
    nrm[bb2][dp] = s0 * s0 + s1 * s1;
    __syncthreads();
    if (t < 32) {
        float qn = 0.f;
#pragma unroll
        for (int d = 0; d < 8; ++d) qn += nrm[t][d];
        cf[t] = qn / ((1.f + qn) * sqrtf(qn));
    }
    __syncthreads();
    float cs = cf[bb2];
    float* o = dst + (size_t)(bt2 * 32 + bb2) * (OUT_NUM * OUT_DIM) + j * OUT_DIM + dp * 2;
    o[0] = s0 * cs;
    o[1] = s1 * cs;
}

// ---- p3 (ALL-j): bp[bq*8+c][i][0..9] = prev + sum_d Wt[j,d,k] * sum_b vt[b,j,d]*x[b,k] ----
// One block per (kt=256k, bq=32b): x-slice staged in LDS ONCE, re-used by all 10 j.
// x LLC traffic per launch: 94 MB -> 9.4 MB (the measured 6.6 TB/s LLC roofline was the cost).
// v loads stay block-uniform (b,j loop vars) -> s_load; xs reads 2-way-bank = free.
__global__ __launch_bounds__(256, 4) void k_p3(const float* __restrict__ x,
                                               const float* __restrict__ vt,
                                               const float* __restrict__ Wt,
                                               float* __restrict__ bp, int it) {
    __shared__ float xs[32 * 256];   // 32 KB
    int u = blockIdx.x, t = threadIdx.x;
    int kt = u % 36, bq = u / 36;    // 36 k-tiles x 8 b-slices
    int k0 = kt * 256;
    int b0 = bq * 32;
    {   // stage: per instr one wave reads 1 KB contiguous (64 x float4) — fully coalesced
        int l = t & 63, wv = t >> 6;
#pragma unroll
        for (int rr = 0; rr < 8; ++rr) {
            int row = rr * 4 + wv;
            float4 v4 = *reinterpret_cast<const float4*>(
                &x[(size_t)(b0 + row) * KTOT + k0 + l * 4]);
            *reinterpret_cast<float4*>(&xs[row * 256 + l * 4]) = v4;
        }
    }
    __syncthreads();
    int k = k0 + t;
    int c = k / IN_NUM, i = k - c * IN_NUM;
    size_t idx = (size_t)(bq * 8 + c) * (IN_NUM * OUT_NUM) + (size_t)i * OUT_NUM;
    for (int j = 0; j < OUT_NUM; ++j) {           // not unrolled: keeps code small, s_load per iter
        const float* vjb = vt + (size_t)b0 * (OUT_NUM * OUT_DIM) + j * OUT_DIM;
        float macc[16];
#pragma unroll
        for (int d = 0; d < 16; ++d) macc[d] = 0.f;
#pragma unroll 4
        for (int b = 0; b < 32; ++b) {
            float xv = xs[b * 256 + t];
            const float* vb = vjb + (size_t)b * (OUT_NUM * OUT_DIM);   // block-uniform -> s_load
#pragma unroll
            for (int d = 0; d < 16; ++d) macc[d] += vb[d] * xv;
        }
        float bs = 0.f;
#pragma unroll
        for (int d = 0; d < 16; ++d)
            bs += macc[d] * Wt[(size_t)(j * OUT_DIM + d) * KTOT + k];
        float prev = (it == 0) ? 0.f : bp[idx + j];
        bp[idx + j] = prev + bs;
    }
}

extern "C" void kernel_launch(void* const* d_in, const int* in_sizes, int n_in,
                              void* d_out, int out_size, void* d_ws, size_t ws_size,
                              hipStream_t stream) {
    const float* x = (const float*)d_in[0];   // [256][8][1152]
    const float* W = (const float*)d_in[1];   // [1152][10][16][8]
    float* out = (float*)d_out;               // [256][10][16][1]
    float* ws = (float*)d_ws;

    float* spart = ws + OFF_SPART;
    float* bp    = ws + OFF_BP;
    float* vt    = ws + OFF_VT;
    float* Wt    = ws + OFF_WT;
    float* Wt2   = ws + OFF_WT2;

    k_prep<<<dim3(360), dim3(256), 0, stream>>>(W, Wt, Wt2);
    for (int it = 0; it < 3; ++it) {
        k_p1<<<dim3(960), dim3(256), 0, stream>>>(x, Wt2, bp, spart, it);
        k_p2<<<dim3(80), dim3(256), 0, stream>>>(spart, it == 2 ? out : vt);
        if (it < 2) k_p3<<<dim3(288), dim3(256), 0, stream>>>(x, vt, Wt, bp, it);
    }
}

// Round 18
// 162.602 us; speedup vs baseline: 1.1041x; 1.1041x over previous
//
#include <hip/hip_runtime.h>

#define IN_NUM 1152
#define OUT_NUM 10
#define OUT_DIM 16
#define IN_DIM 8
#define NB 256
#define KTOT 9216

// workspace float offsets
#define OFF_SPART 0
#define SZ_SPART (96 * OUT_NUM * OUT_DIM * NB)        // 3,932,160
#define OFF_BP (OFF_SPART + SZ_SPART)
#define SZ_BP (64 * IN_NUM * OUT_NUM)                 // 737,280 (8 bs x 8 c rows)
#define OFF_VT (OFF_BP + SZ_BP)
#define SZ_VT (NB * OUT_NUM * OUT_DIM)                // 40,960
#define OFF_WT (OFF_VT + SZ_VT)
#define SZ_WT (OUT_NUM * OUT_DIM * KTOT)              // Wt[j][d*8+c][i]
#define OFF_WT2 (OFF_WT + SZ_WT)
#define SZ_WT2 (OUT_NUM * KTOT * OUT_DIM)             // Wt2[j][k][d]

typedef short bf16x8 __attribute__((ext_vector_type(8)));
typedef float f32x4 __attribute__((ext_vector_type(4)));

__device__ __forceinline__ unsigned short f2bf(float f) {
    unsigned u = __float_as_uint(f);
    u = (u + 0x7FFFu + ((u >> 16) & 1u)) >> 16;   // round-to-nearest-even
    return (unsigned short)u;
}

// ---- p1 (MFMA): spart[isp][j][d][b] = sum_k (ldc[k]*W[k,d]) * x[b,k] ----
// it==0: prep fused — atT built from raw W; this block emits its own Wt/Wt2 slice.
__global__ __launch_bounds__(256, 4) void k_p1(const float* __restrict__ x,
                                               const float* __restrict__ W,
                                               float* __restrict__ Wt,
                                               float* __restrict__ Wt2,
                                               const float* __restrict__ bp,
                                               float* __restrict__ spart, int it) {
    __shared__ float ldc[96];
    __shared__ unsigned short atT[16][100];
    int w = blockIdx.x, t = threadIdx.x;
    int g8 = w / 80, r = w - g8 * 80;
    int j = r >> 3, isp = g8 * 8 + (r & 7);   // same-isp j-group 8 apart -> same XCD
    int cch = isp / 12;
    int i0 = (isp - cch * 12) * 96;
    int k0 = isp * 96;
    if (it > 0 && t < 96) {
        int i = i0 + t;
        float bt_[OUT_NUM];
#pragma unroll
        for (int jp = 0; jp < OUT_NUM; ++jp) bt_[jp] = 0.f;
#pragma unroll 4
        for (int row = 0; row < 64; ++row) {   // 8 bs x 8 c partial rows
            const float2* p2 = reinterpret_cast<const float2*>(
                &bp[(size_t)row * (IN_NUM * OUT_NUM) + i * OUT_NUM]);
#pragma unroll
            for (int q = 0; q < 5; ++q) {
                float2 v = p2[q];
                bt_[q * 2] += v.x; bt_[q * 2 + 1] += v.y;
            }
        }
        float m = -1e30f;
#pragma unroll
        for (int jp = 0; jp < OUT_NUM; ++jp) { bt_[jp] *= (1.f / NB); m = fmaxf(m, bt_[jp]); }
        float s = 0.f;
#pragma unroll
        for (int jp = 0; jp < OUT_NUM; ++jp) { bt_[jp] = __expf(bt_[jp] - m); s += bt_[jp]; }
        ldc[t] = bt_[j] / s;
    }
    __syncthreads();
    if (it == 0) {
        // prep fused: read raw W slice, emit Wt + Wt2 slices, build atT with c=0.1
        for (int e = t; e < 1536; e += 256) {
            int d = e / 96, kk = e - d * 96;
            float raw = W[(size_t)(i0 + kk) * 1280 + j * 128 + d * 8 + cch];
            Wt[(size_t)(j * 128 + d * 8 + cch) * IN_NUM + i0 + kk] = raw;
            Wt2[((size_t)j * KTOT + cch * IN_NUM + i0 + kk) * OUT_DIM + d] = raw;
            atT[d][kk] = f2bf(0.1f * raw);
        }
    } else {
        for (int e = t; e < 1536; e += 256) {
            int d = e & 15, kk = e >> 4;
            atT[d][kk] = f2bf(ldc[kk] * Wt2[((size_t)j * KTOT + k0 + kk) * OUT_DIM + d]);
        }
    }
    __syncthreads();
    int lane = t & 63, wv = t >> 6;
    int lg = lane >> 4, lm = lane & 15;
    bf16x8 bfr[3];
#pragma unroll
    for (int ks = 0; ks < 3; ++ks) {
        const unsigned short* p0 = &atT[lm][ks * 32 + lg * 4];
        ushort4 u0 = *reinterpret_cast<const ushort4*>(p0);
        ushort4 u1 = *reinterpret_cast<const ushort4*>(p0 + 16);
        bfr[ks][0] = (short)u0.x; bfr[ks][1] = (short)u0.y;
        bfr[ks][2] = (short)u0.z; bfr[ks][3] = (short)u0.w;
        bfr[ks][4] = (short)u1.x; bfr[ks][5] = (short)u1.y;
        bfr[ks][6] = (short)u1.z; bfr[ks][7] = (short)u1.w;
    }
    float* sp = spart + ((size_t)isp * OUT_NUM + j) * (OUT_DIM * NB);
#pragma unroll
    for (int tb = 0; tb < 4; ++tb) {
        int tbase = (wv * 4 + tb) * 16;
        const float* xr = x + (size_t)(tbase + lm) * KTOT + k0 + lg * 4;
        f32x4 acc = {0.f, 0.f, 0.f, 0.f};
#pragma unroll
        for (int ks = 0; ks < 3; ++ks) {
            float4 a0 = *reinterpret_cast<const float4*>(xr + ks * 32);
            float4 a1 = *reinterpret_cast<const float4*>(xr + ks * 32 + 16);
            bf16x8 af;
            af[0] = (short)f2bf(a0.x); af[1] = (short)f2bf(a0.y);
            af[2] = (short)f2bf(a0.z); af[3] = (short)f2bf(a0.w);
            af[4] = (short)f2bf(a1.x); af[5] = (short)f2bf(a1.y);
            af[6] = (short)f2bf(a1.z); af[7] = (short)f2bf(a1.w);
            acc = __builtin_amdgcn_mfma_f32_16x16x32_bf16(af, bfr[ks], acc, 0, 0, 0);
        }
        *reinterpret_cast<float4*>(&sp[(size_t)lm * NB + tbase + lg * 4]) =
            make_float4(acc[0], acc[1], acc[2], acc[3]);
    }
}

// ---- p2: reduce spart over isp, squash, write dst[b][j][d] (validated form) ----
__global__ __launch_bounds__(256, 4) void k_p2(const float* __restrict__ spart,
                                               float* __restrict__ dst) {
    __shared__ float smem[4672];
    float (*red)[32][17] = (float (*)[32][17])smem;
    float (*nrm)[9] = (float (*)[9])(smem + 4352);
    float* cf = smem + 4640;
    int wvar = blockIdx.x, t = threadIdx.x;
    int j = wvar >> 3, bt2 = wvar & 7;
    int ie = t >> 5, bb = t & 31;
    int b = bt2 * 32 + bb;
    float acc[16];
#pragma unroll
    for (int d = 0; d < 16; ++d) acc[d] = 0.f;
    for (int q = 0; q < 12; ++q) {
        int isp = ie * 12 + q;
        const float* sp = spart + (size_t)(isp * OUT_NUM + j) * (OUT_DIM * NB) + b;
#pragma unroll
        for (int d = 0; d < 16; ++d) acc[d] += sp[d * NB];
    }
#pragma unroll
    for (int d = 0; d < 16; ++d) red[ie][bb][d] = acc[d];
    __syncthreads();
    int bb2 = t >> 3, dp = t & 7;
    float s0 = 0.f, s1 = 0.f;
#pragma unroll
    for (int e = 0; e < 8; ++e) { s0 += red[e][bb2][dp * 2]; s1 += red[e][bb2][dp * 2 + 1]; }
    nrm[bb2][dp] = s0 * s0 + s1 * s1;
    __syncthreads();
    if (t < 32) {
        float qn = 0.f;
#pragma unroll
        for (int d = 0; d < 8; ++d) qn += nrm[t][d];
        cf[t] = qn / ((1.f + qn) * sqrtf(qn));
    }
    __syncthreads();
    float cs = cf[bb2];
    float* o = dst + (size_t)(bt2 * 32 + bb2) * (OUT_NUM * OUT_DIM) + j * OUT_DIM + dp * 2;
    o[0] = s0 * cs;
    o[1] = s1 * cs;
}

// ---- p3: bp[bs*8+c][i][j] = prev + sum_d Wt[j,d,k] * sum_b vs[b,j,d]*xs[b,k] ----
// 576 blocks (72 kt x 8 bs) = 2.25 blk/CU (9 waves/CU TLP). x AND vt staged in LDS:
// inner loop = per-lane b32 (2-way free) + same-address b128 (HW broadcast) + 16 FMA.
// Traffic 94 -> 28 MB; no s_load chains (R17's failure). Thread = (kl 128, jh 2), 5 j each.
__global__ __launch_bounds__(256, 4) void k_p3(const float* __restrict__ x,
                                               const float* __restrict__ vt,
                                               const float* __restrict__ Wt,
                                               float* __restrict__ bp, int it) {
    __shared__ float xs[32 * 128];   // 16 KB [b][k]
    __shared__ float vs[32 * 160];   // 20 KB [b][j*16+d]
    int u = blockIdx.x, t = threadIdx.x;
    int kt = u % 72, bs = u / 72;
    int k0 = kt * 128, b0 = bs * 32;
    // stage xs: 1024 float4, coalesced (32 float4 per b-row)
#pragma unroll
    for (int p = 0; p < 4; ++p) {
        int e = p * 256 + t;
        int row = e >> 5, c4 = e & 31;
        *reinterpret_cast<float4*>(&xs[row * 128 + c4 * 4]) =
            *reinterpret_cast<const float4*>(&x[(size_t)(b0 + row) * KTOT + k0 + c4 * 4]);
    }
    // stage vs: contiguous 20 KB copy (vt is [b][160] b-major)
    {
        const float4* src = reinterpret_cast<const float4*>(vt + (size_t)b0 * 160);
        float4* dst4 = reinterpret_cast<float4*>(vs);
#pragma unroll
        for (int p = 0; p < 5; ++p) dst4[p * 256 + t] = src[p * 256 + t];
    }
    __syncthreads();
    int jh = t >> 7, kl = t & 127;   // jh wave-uniform
    int k = k0 + kl;
    int c = k / IN_NUM, i = k - c * IN_NUM;
    size_t idx = ((size_t)(bs * 8 + c) * IN_NUM + i) * OUT_NUM + jh * 5;
#pragma unroll
    for (int jj = 0; jj < 5; ++jj) {
        int j = jh * 5 + jj;
        float macc[16];
#pragma unroll
        for (int d = 0; d < 16; ++d) macc[d] = 0.f;
#pragma unroll 8
        for (int b = 0; b < 32; ++b) {
            float xv = xs[b * 128 + kl];
            const float* vb = &vs[b * 160 + j * 16];   // same addr all lanes -> broadcast
#pragma unroll
            for (int d = 0; d < 16; ++d) macc[d] += vb[d] * xv;
        }
        float bsum = 0.f;
#pragma unroll
        for (int d = 0; d < 16; ++d)
            bsum += macc[d] * Wt[(size_t)(j * OUT_DIM + d) * KTOT + k];   // coalesced over kl
        bp[idx + jj] = (it == 0) ? bsum : (bp[idx + jj] + bsum);
    }
}

extern "C" void kernel_launch(void* const* d_in, const int* in_sizes, int n_in,
                              void* d_out, int out_size, void* d_ws, size_t ws_size,
                              hipStream_t stream) {
    const float* x = (const float*)d_in[0];   // [256][8][1152]
    const float* W = (const float*)d_in[1];   // [1152][10][16][8]
    float* out = (float*)d_out;               // [256][10][16][1]
    float* ws = (float*)d_ws;

    float* spart = ws + OFF_SPART;
    float* bp    = ws + OFF_BP;
    float* vt    = ws + OFF_VT;
    float* Wt    = ws + OFF_WT;
    float* Wt2   = ws + OFF_WT2;

    for (int it = 0; it < 3; ++it) {
        k_p1<<<dim3(960), dim3(256), 0, stream>>>(x, W, Wt, Wt2, bp, spart, it);
        k_p2<<<dim3(80), dim3(256), 0, stream>>>(spart, it == 2 ? out : vt);
        if (it < 2) k_p3<<<dim3(576), dim3(256), 0, stream>>>(x, vt, Wt, bp, it);
    }
}

// Round 19
// 120.561 us; speedup vs baseline: 1.4891x; 1.3487x over previous
//
#include <hip/hip_runtime.h>

#define IN_NUM 1152
#define OUT_NUM 10
#define OUT_DIM 16
#define IN_DIM 8
#define NB 256
#define KTOT 9216

// workspace float offsets
#define OFF_SPART 0
#define SZ_SPART (96 * OUT_NUM * OUT_DIM * NB)        // 3,932,160
#define OFF_BP (OFF_SPART + SZ_SPART)
#define SZ_BP (32 * IN_NUM * OUT_NUM)                 // 368,640 (4 bq x 8 c rows)
#define OFF_VT (OFF_BP + SZ_BP)
#define SZ_VT (NB * OUT_NUM * OUT_DIM)                // 40,960
#define OFF_WT2 (OFF_VT + SZ_VT)
#define SZ_WT2 (OUT_NUM * KTOT * OUT_DIM)             // Wt2[j][k][d] f32
#define OFF_WTBF (OFF_WT2 + SZ_WT2)
#define SZ_WTBF (OUT_NUM * OUT_DIM * KTOT / 2)        // Wtbf[j][d][k] bf16
#define OFF_XBF (OFF_WTBF + SZ_WTBF)
#define SZ_XBF (NB * KTOT / 2)                        // xbf[b][k] bf16

typedef short bf16x8 __attribute__((ext_vector_type(8)));
typedef float f32x4 __attribute__((ext_vector_type(4)));

__device__ __forceinline__ unsigned short f2bf(float f) {
    unsigned u = __float_as_uint(f);
    u = (u + 0x7FFFu + ((u >> 16) & 1u)) >> 16;   // round-to-nearest-even
    return (unsigned short)u;
}
__device__ __forceinline__ float bf2f(unsigned short h) {
    return __uint_as_float((unsigned)h << 16);
}

// ---- prep: Wt2[j][c*1152+i][d] f32, Wtbf[j][d*8+c][i] bf16, xbf[b][k] bf16 ----
__global__ __launch_bounds__(256) void k_prep(const float* __restrict__ x,
                                              const float* __restrict__ W,
                                              float* __restrict__ Wt2,
                                              unsigned short* __restrict__ Wtbf,
                                              unsigned short* __restrict__ xbf) {
    int u = blockIdx.x, t = threadIdx.x;
    if (u < 360) {
        __shared__ float lds2[32][129];
        int itile = u / 10, j = u - itile * 10;
        int i0 = itile * 32;
        int r0 = t >> 5, c4b = t & 31;
#pragma unroll
        for (int rr = 0; rr < 4; ++rr) {
            int rrow = rr * 8 + r0;
            float4 w4 = *reinterpret_cast<const float4*>(
                &W[(size_t)(i0 + rrow) * 1280 + j * 128 + c4b * 4]);
            lds2[rrow][c4b * 4 + 0] = w4.x; lds2[rrow][c4b * 4 + 1] = w4.y;
            lds2[rrow][c4b * 4 + 2] = w4.z; lds2[rrow][c4b * 4 + 3] = w4.w;
        }
        __syncthreads();
        int ii = t & 31, dcq = t >> 5;
#pragma unroll
        for (int rr = 0; rr < 16; ++rr) {
            int dc = rr * 8 + dcq;
            Wtbf[(size_t)(j * 128 + dc) * IN_NUM + i0 + ii] = f2bf(lds2[ii][dc]);
        }
        int d4 = t & 3, ii2 = (t >> 2) & 31, ch0 = t >> 7;
#pragma unroll
        for (int c2 = 0; c2 < 4; ++c2) {
            int c = c2 * 2 + ch0;
            float4 o;
            o.x = lds2[ii2][(d4 * 4 + 0) * 8 + c];
            o.y = lds2[ii2][(d4 * 4 + 1) * 8 + c];
            o.z = lds2[ii2][(d4 * 4 + 2) * 8 + c];
            o.w = lds2[ii2][(d4 * 4 + 3) * 8 + c];
            *reinterpret_cast<float4*>(
                &Wt2[((size_t)j * KTOT + c * IN_NUM + i0 + ii2) * OUT_DIM + d4 * 4]) = o;
        }
    } else {
        // x -> bf16, 144 blocks x 16384 floats, fully coalesced
        int u2 = u - 360;
        const float4* x4 = reinterpret_cast<const float4*>(x);
#pragma unroll
        for (int p = 0; p < 16; ++p) {
            int e4 = u2 * 4096 + p * 256 + t;
            float4 v = x4[e4];
            ushort4 o;
            o.x = f2bf(v.x); o.y = f2bf(v.y); o.z = f2bf(v.z); o.w = f2bf(v.w);
            *reinterpret_cast<ushort4*>(&xbf[(size_t)e4 * 4]) = o;
        }
    }
}

// ---- p1 (MFMA, R16-validated verbatim): spart[isp][j][d][b] = sum_k (ldc[k]*W[k,d]) * x[b,k] ----
__global__ __launch_bounds__(256, 4) void k_p1(const float* __restrict__ x,
                                               const float* __restrict__ Wt2,
                                               const float* __restrict__ bp,
                                               float* __restrict__ spart, int it) {
    __shared__ float ldc[96];
    __shared__ unsigned short atT[16][100];
    int w = blockIdx.x, t = threadIdx.x;
    int g8 = w / 80, r = w - g8 * 80;
    int j = r >> 3, isp = g8 * 8 + (r & 7);   // same-isp j-group 8 apart -> same XCD
    int cch = isp / 12;
    int i0 = (isp - cch * 12) * 96;
    int k0 = isp * 96;
    if (t < 96) {
        float cv;
        if (it == 0) {
            cv = 0.1f;
        } else {
            int i = i0 + t;
            float bt_[OUT_NUM];
#pragma unroll
            for (int jp = 0; jp < OUT_NUM; ++jp) bt_[jp] = 0.f;
#pragma unroll 4
            for (int row = 0; row < 32; ++row) {
                const float2* p2 = reinterpret_cast<const float2*>(
                    &bp[(size_t)row * (IN_NUM * OUT_NUM) + i * OUT_NUM]);
#pragma unroll
                for (int q = 0; q < 5; ++q) {
                    float2 v = p2[q];
                    bt_[q * 2] += v.x; bt_[q * 2 + 1] += v.y;
                }
            }
            float m = -1e30f;
#pragma unroll
            for (int jp = 0; jp < OUT_NUM; ++jp) { bt_[jp] *= (1.f / NB); m = fmaxf(m, bt_[jp]); }
            float s = 0.f;
#pragma unroll
            for (int jp = 0; jp < OUT_NUM; ++jp) { bt_[jp] = __expf(bt_[jp] - m); s += bt_[jp]; }
            cv = bt_[j] / s;
        }
        ldc[t] = cv;
    }
    __syncthreads();
    for (int e = t; e < 1536; e += 256) {
        int d = e & 15, kk = e >> 4;
        atT[d][kk] = f2bf(ldc[kk] * Wt2[((size_t)j * KTOT + k0 + kk) * OUT_DIM + d]);
    }
    __syncthreads();
    int lane = t & 63, wv = t >> 6;
    int lg = lane >> 4, lm = lane & 15;
    bf16x8 bfr[3];
#pragma unroll
    for (int ks = 0; ks < 3; ++ks) {
        const unsigned short* p0 = &atT[lm][ks * 32 + lg * 4];
        ushort4 u0 = *reinterpret_cast<const ushort4*>(p0);
        ushort4 u1 = *reinterpret_cast<const ushort4*>(p0 + 16);
        bfr[ks][0] = (short)u0.x; bfr[ks][1] = (short)u0.y;
        bfr[ks][2] = (short)u0.z; bfr[ks][3] = (short)u0.w;
        bfr[ks][4] = (short)u1.x; bfr[ks][5] = (short)u1.y;
        bfr[ks][6] = (short)u1.z; bfr[ks][7] = (short)u1.w;
    }
    float* sp = spart + ((size_t)isp * OUT_NUM + j) * (OUT_DIM * NB);
#pragma unroll
    for (int tb = 0; tb < 4; ++tb) {
        int tbase = (wv * 4 + tb) * 16;
        const float* xr = x + (size_t)(tbase + lm) * KTOT + k0 + lg * 4;
        f32x4 acc = {0.f, 0.f, 0.f, 0.f};
#pragma unroll
        for (int ks = 0; ks < 3; ++ks) {
            float4 a0 = *reinterpret_cast<const float4*>(xr + ks * 32);
            float4 a1 = *reinterpret_cast<const float4*>(xr + ks * 32 + 16);
            bf16x8 af;
            af[0] = (short)f2bf(a0.x); af[1] = (short)f2bf(a0.y);
            af[2] = (short)f2bf(a0.z); af[3] = (short)f2bf(a0.w);
            af[4] = (short)f2bf(a1.x); af[5] = (short)f2bf(a1.y);
            af[6] = (short)f2bf(a1.z); af[7] = (short)f2bf(a1.w);
            acc = __builtin_amdgcn_mfma_f32_16x16x32_bf16(af, bfr[ks], acc, 0, 0, 0);
        }
        *reinterpret_cast<float4*>(&sp[(size_t)lm * NB + tbase + lg * 4]) =
            make_float4(acc[0], acc[1], acc[2], acc[3]);
    }
}

// ---- p2: reduce spart over isp, squash, write dst[b][j][d] (R11 verbatim) ----
__global__ __launch_bounds__(256, 4) void k_p2(const float* __restrict__ spart,
                                               float* __restrict__ dst) {
    __shared__ float smem[4672];
    float (*red)[32][17] = (float (*)[32][17])smem;
    float (*nrm)[9] = (float (*)[9])(smem + 4352);
    float* cf = smem + 4640;
    int wvar = blockIdx.x, t = threadIdx.x;
    int j = wvar >> 3, bt2 = wvar & 7;
    int ie = t >> 5, bb = t & 31;
    int b = bt2 * 32 + bb;
    float acc[16];
#pragma unroll
    for (int d = 0; d < 16; ++d) acc[d] = 0.f;
    for (int q = 0; q < 12; ++q) {
        int isp = ie * 12 + q;
        const float* sp = spart + (size_t)(isp * OUT_NUM + j) * (OUT_DIM * NB) + b;
#pragma unroll
        for (int d = 0; d < 16; ++d) acc[d] += sp[d * NB];
    }
#pragma unroll
    for (int d = 0; d < 16; ++d) red[ie][bb][d] = acc[d];
    __syncthreads();
    int bb2 = t >> 3, dp = t & 7;
    float s0 = 0.f, s1 = 0.f;
#pragma unroll
    for (int e = 0; e < 8; ++e) { s0 += red[e][bb2][dp * 2]; s1 += red[e][bb2][dp * 2 + 1]; }
    nrm[bb2][dp] = s0 * s0 + s1 * s1;
    __syncthreads();
    if (t < 32) {
        float qn = 0.f;
#pragma unroll
        for (int d = 0; d < 8; ++d) qn += nrm[t][d];
        cf[t] = qn / ((1.f + qn) * sqrtf(qn));
    }
    __syncthreads();
    float cs = cf[bb2];
    float* o = dst + (size_t)(bt2 * 32 + bb2) * (OUT_NUM * OUT_DIM) + j * OUT_DIM + dp * 2;
    o[0] = s0 * cs;
    o[1] = s1 * cs;
}

// ---- p3: R11 body verbatim, x and Wt in bf16 (traffic 118 -> ~60 MB/launch) ----
// v loads stay block-uniform -> s_load (scalar K$ pipe); x/Wt loads coalesced 128B/instr.
__global__ __launch_bounds__(256) void k_p3(const unsigned short* __restrict__ xbf,
                                            const float* __restrict__ vt,
                                            const unsigned short* __restrict__ Wtbf,
                                            float* __restrict__ bp, int it) {
    int u = blockIdx.x, t = threadIdx.x;
    int kt = u % 36;
    int jq = u / 36;
    int j = jq >> 2, bq = jq & 3;
    int k = kt * 256 + t;
    int c = k / IN_NUM, i = k - c * IN_NUM;
    const unsigned short* xk = xbf + k + (size_t)(bq * 64) * KTOT;
    const float* vjb = vt + (size_t)(bq * 64) * (OUT_NUM * OUT_DIM) + j * OUT_DIM;
    float macc[16];
#pragma unroll
    for (int d = 0; d < 16; ++d) macc[d] = 0.f;
#pragma unroll 8
    for (int b = 0; b < 64; ++b) {
        float xv = bf2f(xk[(size_t)b * KTOT]);
        const float* vb = vjb + (size_t)b * (OUT_NUM * OUT_DIM);   // block-uniform -> s_load
#pragma unroll
        for (int d = 0; d < 16; ++d) macc[d] += vb[d] * xv;
    }
    float bs = 0.f;
#pragma unroll
    for (int d = 0; d < 16; ++d)
        bs += macc[d] * bf2f(Wtbf[(size_t)(j * OUT_DIM + d) * KTOT + k]);
    size_t idx = (size_t)(bq * 8 + c) * (IN_NUM * OUT_NUM) + (size_t)i * OUT_NUM + j;
    float prev = (it == 0) ? 0.f : bp[idx];
    bp[idx] = prev + bs;
}

extern "C" void kernel_launch(void* const* d_in, const int* in_sizes, int n_in,
                              void* d_out, int out_size, void* d_ws, size_t ws_size,
                              hipStream_t stream) {
    const float* x = (const float*)d_in[0];   // [256][8][1152]
    const float* W = (const float*)d_in[1];   // [1152][10][16][8]
    float* out = (float*)d_out;               // [256][10][16][1]
    float* ws = (float*)d_ws;

    float* spart = ws + OFF_SPART;
    float* bp    = ws + OFF_BP;
    float* vt    = ws + OFF_VT;
    float* Wt2   = ws + OFF_WT2;
    unsigned short* Wtbf = (unsigned short*)(ws + OFF_WTBF);
    unsigned short* xbf  = (unsigned short*)(ws + OFF_XBF);

    k_prep<<<dim3(504), dim3(256), 0, stream>>>(x, W, Wt2, Wtbf, xbf);
    for (int it = 0; it < 3; ++it) {
        k_p1<<<dim3(960), dim3(256), 0, stream>>>(x, Wt2, bp, spart, it);
        k_p2<<<dim3(80), dim3(256), 0, stream>>>(spart, it == 2 ? out : vt);
        if (it < 2) k_p3<<<dim3(1440), dim3(256), 0, stream>>>(xbf, vt, Wtbf, bp, it);
    }
}